// Round 3
// baseline (313.692 us; speedup 1.0000x reference)
//
#include <hip/hip_runtime.h>

#define NEG_SLOPE 0.2f
#define NPB 256          // nodes per dst-bucket (bucket = dst >> 8)
#define CHUNK 4096       // edges per partition block

typedef _Float16 f16x8 __attribute__((ext_vector_type(8)));
typedef _Float16 f16x4 __attribute__((ext_vector_type(4)));
typedef _Float16 f16x2 __attribute__((ext_vector_type(2)));
typedef float    f32x4 __attribute__((ext_vector_type(4)));
typedef float    f32x8 __attribute__((ext_vector_type(8)));

#if defined(__has_builtin)
#if __has_builtin(__builtin_amdgcn_fdot2)
#define HAVE_FDOT2 1
#endif
#endif

// DPP butterfly add step — pure VALU, no LDS pipe (vs __shfl_xor's ds_bpermute).
// CTRL: 0xB1 = quad_perm(1,0,3,2) (xor1), 0x4E = quad_perm(2,3,0,1) (xor2),
// 0x141 = row_half_mirror (xor4 once quads uniform), 0x140 = row_mirror (xor8
// once 8-groups uniform). CTRL must be a compile-time constant -> template.
template <int CTRL>
__device__ __forceinline__ float dpp_add(float v) {
    int o = __builtin_amdgcn_update_dpp(0, __builtin_bit_cast(int, v),
                                        CTRL, 0xF, 0xF, true);
    return v + __builtin_bit_cast(float, o);
}

// ---------------------------------------------------------------------------
// prep: W transpose->fp16 (blocks 0..255), x fp32->fp16 hi/lo split
// (blocks 256..), bcnt zero (block 0).
// ---------------------------------------------------------------------------
__global__ __launch_bounds__(256) void prep_kernel(
    const float* __restrict__ W0, const float* __restrict__ W1,
    const float* __restrict__ W2, const float* __restrict__ W3,
    _Float16* __restrict__ wt,
    const float* __restrict__ x, _Float16* __restrict__ xh,
    _Float16* __restrict__ xlo, int total, int* __restrict__ bcnt)
{
    int t = threadIdx.x;
    if (blockIdx.x < 256) {
        if (blockIdx.x == 0) bcnt[t] = 0;
        int idx = blockIdx.x * 256 + t;     // 4*128*128
        int m = idx >> 14;
        int k = (idx >> 7) & 127;
        int n = idx & 127;
        const float* W = (m == 0) ? W0 : (m == 1) ? W1 : (m == 2) ? W2 : W3;
        wt[m * 16384 + n * 128 + k] = (_Float16)W[k * 128 + n];
    } else {
        int i = (blockIdx.x - 256) * 256 + t;
        if (i * 2 < total) {
            float2 f = *(const float2*)(x + (size_t)i * 2);
            _Float16 h0 = (_Float16)f.x, h1 = (_Float16)f.y;
            _Float16 l0 = (_Float16)(f.x - (float)h0), l1 = (_Float16)(f.y - (float)h1);
            *(f16x2*)(xh  + (size_t)i * 2) = (f16x2){h0, h1};
            *(f16x2*)(xlo + (size_t)i * 2) = (f16x2){l0, l1};
        }
    }
}

// ---------------------------------------------------------------------------
// fp16 MFMA GEMM, LDS-staged W (34 KB). C = Ah@W + Al@W, fp32 acc.
// ONE launch per layer: each block computes BOTH outputs (Wl and Wr),
// reading its A tile once. W1 staging loads are issued before the out0
// compute loop so their latency hides under the MFMAs; LDS is re-staged.
// ---------------------------------------------------------------------------
__global__ __launch_bounds__(256) void gemm_f16_kernel(
    const _Float16* __restrict__ Ahi, const _Float16* __restrict__ Alo,
    const _Float16* __restrict__ Wt0, const _Float16* __restrict__ Wt1,
    _Float16* __restrict__ Cl, _Float16* __restrict__ Cr, int N)
{
    __shared__ _Float16 ldsW[128 * 136];   // row stride 272 B

    const int tid = threadIdx.x;
    const int wave = tid >> 6;
    const int lane = tid & 63;
    const int mrow = lane & 15;
    const int quad = lane >> 4;
    const int rbase = blockIdx.x * 128 + wave * 32;
    const int sn = tid >> 1, shf = tid & 1;

    // staging loads first (latency overlaps A loads)
    float4 stg[8];
    {
        const float4* gp = (const float4*)(Wt0 + sn * 128 + shf * 64);
#pragma unroll
        for (int j = 0; j < 8; j++) stg[j] = gp[j];
    }

    f16x8 ah[2][4], al[2][4];
#pragma unroll
    for (int rt = 0; rt < 2; rt++) {
        int r = rbase + rt * 16 + mrow;
        if (r > N - 1) r = N - 1;
        const _Float16* pa = Ahi + (size_t)r * 128 + quad * 8;
        const _Float16* pl = Alo + (size_t)r * 128 + quad * 8;
#pragma unroll
        for (int s = 0; s < 4; s++) {
            ah[rt][s] = *(const f16x8*)(pa + s * 32);
            al[rt][s] = *(const f16x8*)(pl + s * 32);
        }
    }

    {
        float4* d = (float4*)&ldsW[sn * 136 + shf * 64];
#pragma unroll
        for (int j = 0; j < 8; j++) d[j] = stg[j];
    }
    __syncthreads();

    // issue W1 staging now — latency hides under out0's MFMA loop
    float4 stg1[8];
    {
        const float4* gp = (const float4*)(Wt1 + sn * 128 + shf * 64);
#pragma unroll
        for (int j = 0; j < 8; j++) stg1[j] = gp[j];
    }

    auto compute_store = [&](_Float16* __restrict__ C) {
        f32x4 acc[2][8];
#pragma unroll
        for (int rt = 0; rt < 2; rt++)
#pragma unroll
            for (int c = 0; c < 8; c++) acc[rt][c] = (f32x4){0.f, 0.f, 0.f, 0.f};

#pragma unroll
        for (int s = 0; s < 4; s++) {
#pragma unroll
            for (int c = 0; c < 8; c++) {
                f16x8 bw = *(const f16x8*)&ldsW[(c * 16 + mrow) * 136 + s * 32 + quad * 8];
                acc[0][c] = __builtin_amdgcn_mfma_f32_16x16x32_f16(ah[0][s], bw, acc[0][c], 0, 0, 0);
                acc[0][c] = __builtin_amdgcn_mfma_f32_16x16x32_f16(al[0][s], bw, acc[0][c], 0, 0, 0);
                acc[1][c] = __builtin_amdgcn_mfma_f32_16x16x32_f16(ah[1][s], bw, acc[1][c], 0, 0, 0);
                acc[1][c] = __builtin_amdgcn_mfma_f32_16x16x32_f16(al[1][s], bw, acc[1][c], 0, 0, 0);
            }
        }

        // D mapping: col = lane&15, row = quad*4 + reg
#pragma unroll
        for (int rt = 0; rt < 2; rt++)
#pragma unroll
            for (int i = 0; i < 4; i++) {
                int r = rbase + rt * 16 + quad * 4 + i;
                if (r < N) {
                    _Float16* cr = C + (size_t)r * 128 + mrow;
#pragma unroll
                    for (int c = 0; c < 8; c++) cr[c * 16] = (_Float16)acc[rt][c][i];
                }
            }
    };

    compute_store(Cl);

    __syncthreads();   // all waves done reading W0
    {
        float4* d = (float4*)&ldsW[sn * 136 + shf * 64];
#pragma unroll
        for (int j = 0; j < 8; j++) d[j] = stg1[j];
    }
    __syncthreads();

    compute_store(Cr);
}

// ---------------------------------------------------------------------------
// Bucketed CSR build (bucket = dst>>8): writes stay CU/XCD-local.
// ---------------------------------------------------------------------------
__global__ __launch_bounds__(256) void histB_kernel(
    const int* __restrict__ ei, int* __restrict__ bcnt, int E)
{
    __shared__ int bh[256];
    int t = threadIdx.x;
    bh[t] = 0;
    __syncthreads();
    int base = blockIdx.x * CHUNK;
#pragma unroll
    for (int j = 0; j < CHUNK / 256; j++) {
        int e = base + t + j * 256;
        if (e < E) atomicAdd(&bh[ei[E + e] >> 8], 1);
    }
    __syncthreads();
    if (bh[t]) atomicAdd(&bcnt[t], bh[t]);
}

__global__ __launch_bounds__(256) void scanB_kernel(
    const int* __restrict__ bcnt, int* __restrict__ bstart,
    int* __restrict__ gcursor, int NB, int E)
{
    __shared__ int s[256];
    int t = threadIdx.x;
    int v = (t < NB) ? bcnt[t] : 0;
    s[t] = v;
    __syncthreads();
    for (int off = 1; off < 256; off <<= 1) {
        int u = (t >= off) ? s[t - off] : 0;
        __syncthreads();
        s[t] += u;
        __syncthreads();
    }
    if (t < NB) { bstart[t] = s[t] - v; gcursor[t] = s[t] - v; }
    if (t == 0) bstart[NB] = E;
}

__global__ __launch_bounds__(256) void passA_kernel(
    const int* __restrict__ ei, int* __restrict__ gcursor,
    int2* __restrict__ staging, int E)
{
    __shared__ int bh[256];
    __shared__ int bbase[256];
    int t = threadIdx.x;
    bh[t] = 0;
    __syncthreads();
    int base = blockIdx.x * CHUNK;
    int srcv[16], dstv[16], rb[16];
#pragma unroll
    for (int j = 0; j < 16; j++) {
        int e = base + t + j * 256;
        if (e < E) {
            int d = ei[E + e];
            srcv[j] = ei[e];
            dstv[j] = d;
            int bk = d >> 8;
            int r = atomicAdd(&bh[bk], 1);
            rb[j] = (r << 8) | bk;
        } else rb[j] = -1;
    }
    __syncthreads();
    if (bh[t]) bbase[t] = atomicAdd(&gcursor[t], bh[t]);
    __syncthreads();
#pragma unroll
    for (int j = 0; j < 16; j++) {
        if (rb[j] >= 0) {
            int bk = rb[j] & 255, r = rb[j] >> 8;
            staging[bbase[bk] + r] = make_int2(srcv[j], dstv[j]);
        }
    }
}

__global__ __launch_bounds__(256) void passB_kernel(
    const int2* __restrict__ staging, const int* __restrict__ bstart,
    int* __restrict__ start, int* __restrict__ sorted_src, int N, int E)
{
    __shared__ int lhist[256], lscan[256], lcur[256];
    int b = blockIdx.x, t = threadIdx.x;
    int r0 = bstart[b], r1 = bstart[b + 1];
    lhist[t] = 0;
    __syncthreads();
    for (int i = r0 + t; i < r1; i += 256) atomicAdd(&lhist[staging[i].y & 255], 1);
    __syncthreads();
    int v = lhist[t];
    lscan[t] = v;
    __syncthreads();
    for (int off = 1; off < 256; off <<= 1) {
        int u = (t >= off) ? lscan[t - off] : 0;
        __syncthreads();
        lscan[t] += u;
        __syncthreads();
    }
    int excl = lscan[t] - v;
    int node = b * NPB + t;
    if (node < N) start[node] = r0 + excl;
    lcur[t] = excl;
    if (b == 0 && t == 0) start[N] = E;
    __syncthreads();
    for (int i = r0 + t; i < r1; i += 256) {
        int2 p = staging[i];
        int rank = atomicAdd(&lcur[p.y & 255], 1);
        sorted_src[r0 + rank] = p.x;
    }
}

// ---------------------------------------------------------------------------
// Fused score+softmax+aggregate.
// One wave per dst node; 16 lanes per edge (f16x8/lane), 4 edges per group.
// ALL loads for the node (up to 8 groups = 32 edges, covering ~99% of
// Poisson(16)-degree nodes) are issued upfront before any compute — one
// memory-latency chain per wave instead of main+tail chains. Every group is
// masked (src clamped to node, e zeroed for iv>=M) so main and tail unify.
// Score reduction via DPP (no LDS pipe); H==2 stops at the 8-lane boundary
// so lanes 0-7 = head 0, 8-15 = head 1. att pre-scaled by log2(e) -> exp2f.
// Self-loop = virtual edge 0.
// ---------------------------------------------------------------------------
template <int H, bool BFOUT>
__global__ __launch_bounds__(256) void gat_fused_kernel(
    const _Float16* __restrict__ xl, const _Float16* __restrict__ xr,
    const float* __restrict__ att, const float* __restrict__ bias,
    const int* __restrict__ start, const int* __restrict__ sorted_src,
    float* __restrict__ outf, _Float16* __restrict__ oh,
    _Float16* __restrict__ ol, int N)
{
    int node = blockIdx.x * 4 + (threadIdx.x >> 6);
    if (node >= N) return;
    const int lane = threadIdx.x & 63;
    const int g  = lane >> 4;          // edge slot 0..3 within a group
    const int hl = lane & 15;          // feature slot: ch [hl*8, hl*8+8)
    const _Float16 NS = (_Float16)NEG_SLOPE;
    const float L2E = 1.44269504f;

    const f16x8 b4 = *(const f16x8*)(xr + (size_t)node * 128 + hl * 8);
    float4 at0 = *(const float4*)(att + hl * 8);
    float4 at1 = *(const float4*)(att + hl * 8 + 4);
#if defined(HAVE_FDOT2)
    f16x2 av0 = {(_Float16)(at0.x * L2E), (_Float16)(at0.y * L2E)};
    f16x2 av1 = {(_Float16)(at0.z * L2E), (_Float16)(at0.w * L2E)};
    f16x2 av2 = {(_Float16)(at1.x * L2E), (_Float16)(at1.y * L2E)};
    f16x2 av3 = {(_Float16)(at1.z * L2E), (_Float16)(at1.w * L2E)};
#else
    f32x8 avf = {at0.x * L2E, at0.y * L2E, at0.z * L2E, at0.w * L2E,
                 at1.x * L2E, at1.y * L2E, at1.z * L2E, at1.w * L2E};
#endif

    auto score = [&](f16x8 a_) -> float {
        f16x8 t = a_ + b4;
        f16x8 u = __builtin_elementwise_max(t, t * NS);
#if defined(HAVE_FDOT2)
        f16x2 u0 = __builtin_shufflevector(u, u, 0, 1);
        f16x2 u1 = __builtin_shufflevector(u, u, 2, 3);
        f16x2 u2 = __builtin_shufflevector(u, u, 4, 5);
        f16x2 u3 = __builtin_shufflevector(u, u, 6, 7);
        return __builtin_amdgcn_fdot2(u0, av0,
               __builtin_amdgcn_fdot2(u1, av1,
               __builtin_amdgcn_fdot2(u2, av2,
               __builtin_amdgcn_fdot2(u3, av3, 0.f, false), false), false), false);
#else
        f32x8 uf = __builtin_convertvector(u, f32x8);
        float p = 0.f;
#pragma unroll
        for (int i = 0; i < 8; i++) p += uf[i] * avf[i];
        return p;
#endif
    };

    // 16-lane (or 8-lane for H==2) butterfly reduce, pure DPP.
    auto red = [&](float p) -> float {
        p = dpp_add<0xB1>(p);            // xor1
        p = dpp_add<0x4E>(p);            // xor2
        p = dpp_add<0x141>(p);           // xor4 (row_half_mirror)
        if (H == 1) p = dpp_add<0x140>(p);   // xor8 (row_mirror)
        return p;
    };

    const int s0 = start[node];
    const int s1 = start[node + 1];
    const int M  = s1 - s0 + 1;        // incl. self-loop at iv==0
    const int K  = (M + 3) >> 2;       // total 4-edge groups (last masked)

    // masked group load: invalid slots clamp to node's own row (e later 0)
    auto loadg = [&](int kk) -> f16x8 {
        int iv = 4 * kk + g;
        int pos = s0 + ((iv > 0) ? iv - 1 : 0);   // sorted_src padded
        int ld = sorted_src[pos];
        int src = (iv == 0 || iv >= M) ? node : ld;
        return *(const f16x8*)(xl + (size_t)src * 128 + hl * 8);
    };

    f32x8 acc = {0.f, 0.f, 0.f, 0.f, 0.f, 0.f, 0.f, 0.f};
    float den = 0.f;

    auto compg = [&](int kk, f16x8 a) {
        float p = red(score(a));
        float e = (4 * kk + g < M) ? exp2f(p) : 0.f;
        den += e;
#pragma unroll
        for (int i = 0; i < 8; i++)
            acc[i] = fmaf((float)a[i], e, acc[i]);   // v_fma_mix-friendly
    };

    f16x8 a0 = loadg(0), a1 = loadg(1), a2 = loadg(2), a3 = loadg(3);
    if (K > 4) {
        f16x8 a4 = loadg(4), a5 = loadg(5), a6 = loadg(6), a7 = loadg(7);
        compg(0, a0); compg(1, a1); compg(2, a2); compg(3, a3);
        compg(4, a4); compg(5, a5); compg(6, a6); compg(7, a7);
        for (int k = 8; k < K; k += 4) {          // rare: degree > 31
            f16x8 b0 = loadg(k),     b1 = loadg(k + 1);
            f16x8 b2 = loadg(k + 2), b3 = loadg(k + 3);
            compg(k, b0); compg(k + 1, b1); compg(k + 2, b2); compg(k + 3, b3);
        }
    } else {
        compg(0, a0); compg(1, a1); compg(2, a2); compg(3, a3);
    }

    // combine the 4 edge-groups (feature-aligned): masks 16 and 32 only.
    den += __shfl_xor(den, 16, 64);
    den += __shfl_xor(den, 32, 64);
#pragma unroll
    for (int i = 0; i < 8; i++) {
        acc[i] += __shfl_xor(acc[i], 16, 64);
        acc[i] += __shfl_xor(acc[i], 32, 64);
    }

    float inv = 1.0f / den;
    float4 bi0 = *(const float4*)(bias + hl * 8);
    float4 bi1 = *(const float4*)(bias + hl * 8 + 4);
    float o[8];
    o[0] = acc[0] * inv + bi0.x;  o[1] = acc[1] * inv + bi0.y;
    o[2] = acc[2] * inv + bi0.z;  o[3] = acc[3] * inv + bi0.w;
    o[4] = acc[4] * inv + bi1.x;  o[5] = acc[5] * inv + bi1.y;
    o[6] = acc[6] * inv + bi1.z;  o[7] = acc[7] * inv + bi1.w;

    if (lane < 16) {
        if (BFOUT) {   // next layer's A: fp16 hi+lo split
            f16x8 hv, lv;
#pragma unroll
            for (int i = 0; i < 8; i++) {
                _Float16 h = (_Float16)o[i];
                hv[i] = h;
                lv[i] = (_Float16)(o[i] - (float)h);
            }
            *(f16x8*)(oh + (size_t)node * 128 + hl * 8) = hv;
            *(f16x8*)(ol + (size_t)node * 128 + hl * 8) = lv;
        } else {
            *(float4*)(outf + (size_t)node * 128 + hl * 8) =
                make_float4(o[0], o[1], o[2], o[3]);
            *(float4*)(outf + (size_t)node * 128 + hl * 8 + 4) =
                make_float4(o[4], o[5], o[6], o[7]);
        }
    }
}

// ---------------------------------------------------------------------------
extern "C" void kernel_launch(void* const* d_in, const int* in_sizes, int n_in,
                              void* d_out, int out_size, void* d_ws, size_t ws_size,
                              hipStream_t stream)
{
    const float* x    = (const float*)d_in[0];
    const int*   ei   = (const int*)d_in[1];
    const float* Wl1  = (const float*)d_in[3];
    const float* Wr1  = (const float*)d_in[4];
    const float* att1 = (const float*)d_in[5];
    const float* b1   = (const float*)d_in[6];
    const float* Wl2  = (const float*)d_in[7];
    const float* Wr2  = (const float*)d_in[8];
    const float* att2 = (const float*)d_in[9];
    const float* b2   = (const float*)d_in[10];
    float* out = (float*)d_out;

    const int N  = in_sizes[0] / 128;
    const int E  = in_sizes[1] / 2;
    const int NB = (N + NPB - 1) / NPB;

    const size_t nf = (size_t)N * 128;
    _Float16* xlf  = (_Float16*)d_ws;                 // nf fp16 (gather array)
    _Float16* xrf  = xlf + nf;                        // nf fp16
    _Float16* ah   = xrf + nf;                        // nf fp16 (A hi: x, then h)
    _Float16* al   = ah + nf;                         // nf fp16 (A lo)
    _Float16* wt   = al + nf;                         // 4*16384 fp16
    int* bcnt      = (int*)(wt + 4 * 16384);          // 256
    int* bstart    = bcnt + 256;                      // NB+1 (<=257)
    int* gcursor   = bstart + 257;                    // 256
    int* start     = gcursor + 256;                   // N+1
    size_t stgoff  = ((size_t)(start + N + 1) + 7) & ~(size_t)7;
    int2* staging  = (int2*)stgoff;                   // E int2
    int* sorted_src = (int*)(staging + E);            // E + 64 (padded)

    const int grid_chunk = (E + CHUNK - 1) / CHUNK;
    const int node_grid  = (N + 3) / 4;
    const int gemm_gx    = (N + 127) / 128;
    const int split_grid = (int)((nf / 2 + 255) / 256);

    // ---- prep: W->fp16 transposed, x split, bcnt zero ----
    prep_kernel<<<256 + split_grid, 256, 0, stream>>>(
        Wl1, Wr1, Wl2, Wr2, wt, x, ah, al, (int)nf, bcnt);

    // ---- bucketed CSR build (shared by both layers) ----
    histB_kernel<<<grid_chunk, 256, 0, stream>>>(ei, bcnt, E);
    scanB_kernel<<<1, 256, 0, stream>>>(bcnt, bstart, gcursor, NB, E);
    passA_kernel<<<grid_chunk, 256, 0, stream>>>(ei, gcursor, staging, E);
    passB_kernel<<<NB, 256, 0, stream>>>(staging, bstart, start, sorted_src, N, E);

    // ---- Layer 1: heads=2, ch=64 ----
    gemm_f16_kernel<<<gemm_gx, 256, 0, stream>>>(
        ah, al, wt + 0 * 16384, wt + 1 * 16384, xlf, xrf, N);
    gat_fused_kernel<2, true><<<node_grid, 256, 0, stream>>>(
        xlf, xrf, att1, b1, start, sorted_src, nullptr, ah, al, N);

    // ---- Layer 2: heads=1, ch=128 ----
    gemm_f16_kernel<<<gemm_gx, 256, 0, stream>>>(
        ah, al, wt + 2 * 16384, wt + 3 * 16384, xlf, xrf, N);
    gat_fused_kernel<1, false><<<node_grid, 256, 0, stream>>>(
        xlf, xrf, att2, b2, start, sorted_src, out, nullptr, nullptr, N);
}

// Round 4
// 286.450 us; speedup vs baseline: 1.0951x; 1.0951x over previous
//
#include <hip/hip_runtime.h>

#define NEG_SLOPE 0.2f
#define NPB 256          // nodes per dst-bucket (bucket = dst >> 8)
#define CHUNK 4096       // edges per partition block
#define BCAP 5120        // padded bucket capacity (expected fill 4096, +16 sigma)

typedef _Float16 f16x8 __attribute__((ext_vector_type(8)));
typedef _Float16 f16x4 __attribute__((ext_vector_type(4)));
typedef _Float16 f16x2 __attribute__((ext_vector_type(2)));
typedef float    f32x4 __attribute__((ext_vector_type(4)));
typedef float    f32x8 __attribute__((ext_vector_type(8)));

#if defined(__has_builtin)
#if __has_builtin(__builtin_amdgcn_fdot2)
#define HAVE_FDOT2 1
#endif
#endif

__device__ __forceinline__ f32x8 cvt8(f16x8 v) {
    return __builtin_convertvector(v, f32x8);
}

// DPP butterfly add step — pure VALU, no LDS pipe (vs __shfl_xor's ds_bpermute).
// CTRL: 0xB1 = quad_perm(1,0,3,2) (xor1), 0x4E = quad_perm(2,3,0,1) (xor2),
// 0x141 = row_half_mirror (xor4 once quads uniform), 0x140 = row_mirror (xor8
// once 8-groups uniform). CTRL must be a compile-time constant -> template.
template <int CTRL>
__device__ __forceinline__ float dpp_add(float v) {
    int o = __builtin_amdgcn_update_dpp(0, __builtin_bit_cast(int, v),
                                        CTRL, 0xF, 0xF, true);
    return v + __builtin_bit_cast(float, o);
}

// ---------------------------------------------------------------------------
// prep: W transpose->fp16 (blocks 0..255), x fp32->fp16 hi/lo split
// (blocks 256..), gcursor init to bucket bases (block 0).
// ---------------------------------------------------------------------------
__global__ __launch_bounds__(256) void prep_kernel(
    const float* __restrict__ W0, const float* __restrict__ W1,
    const float* __restrict__ W2, const float* __restrict__ W3,
    _Float16* __restrict__ wt,
    const float* __restrict__ x, _Float16* __restrict__ xh,
    _Float16* __restrict__ xlo, int total, int* __restrict__ gcursor)
{
    int t = threadIdx.x;
    if (blockIdx.x < 256) {
        if (blockIdx.x == 0) gcursor[t] = t * BCAP;
        int idx = blockIdx.x * 256 + t;     // 4*128*128
        int m = idx >> 14;
        int k = (idx >> 7) & 127;
        int n = idx & 127;
        const float* W = (m == 0) ? W0 : (m == 1) ? W1 : (m == 2) ? W2 : W3;
        wt[m * 16384 + n * 128 + k] = (_Float16)W[k * 128 + n];
    } else {
        int i = (blockIdx.x - 256) * 256 + t;
        if (i * 2 < total) {
            float2 f = *(const float2*)(x + (size_t)i * 2);
            _Float16 h0 = (_Float16)f.x, h1 = (_Float16)f.y;
            _Float16 l0 = (_Float16)(f.x - (float)h0), l1 = (_Float16)(f.y - (float)h1);
            *(f16x2*)(xh  + (size_t)i * 2) = (f16x2){h0, h1};
            *(f16x2*)(xlo + (size_t)i * 2) = (f16x2){l0, l1};
        }
    }
}

// ---------------------------------------------------------------------------
// fp16 MFMA GEMM, LDS-staged W (34 KB). C = Ah@W + Al@W, fp32 acc.
// ONE launch per layer: each block computes BOTH outputs (Wl and Wr),
// reading its A tile once. W1 staging loads are issued before the out0
// compute loop so their latency hides under the MFMAs; LDS is re-staged.
// ---------------------------------------------------------------------------
__global__ __launch_bounds__(256) void gemm_f16_kernel(
    const _Float16* __restrict__ Ahi, const _Float16* __restrict__ Alo,
    const _Float16* __restrict__ Wt0, const _Float16* __restrict__ Wt1,
    _Float16* __restrict__ Cl, _Float16* __restrict__ Cr, int N)
{
    __shared__ _Float16 ldsW[128 * 136];   // row stride 272 B

    const int tid = threadIdx.x;
    const int wave = tid >> 6;
    const int lane = tid & 63;
    const int mrow = lane & 15;
    const int quad = lane >> 4;
    const int rbase = blockIdx.x * 128 + wave * 32;
    const int sn = tid >> 1, shf = tid & 1;

    // staging loads first (latency overlaps A loads)
    float4 stg[8];
    {
        const float4* gp = (const float4*)(Wt0 + sn * 128 + shf * 64);
#pragma unroll
        for (int j = 0; j < 8; j++) stg[j] = gp[j];
    }

    f16x8 ah[2][4], al[2][4];
#pragma unroll
    for (int rt = 0; rt < 2; rt++) {
        int r = rbase + rt * 16 + mrow;
        if (r > N - 1) r = N - 1;
        const _Float16* pa = Ahi + (size_t)r * 128 + quad * 8;
        const _Float16* pl = Alo + (size_t)r * 128 + quad * 8;
#pragma unroll
        for (int s = 0; s < 4; s++) {
            ah[rt][s] = *(const f16x8*)(pa + s * 32);
            al[rt][s] = *(const f16x8*)(pl + s * 32);
        }
    }

    {
        float4* d = (float4*)&ldsW[sn * 136 + shf * 64];
#pragma unroll
        for (int j = 0; j < 8; j++) d[j] = stg[j];
    }
    __syncthreads();

    // issue W1 staging now — latency hides under out0's MFMA loop
    float4 stg1[8];
    {
        const float4* gp = (const float4*)(Wt1 + sn * 128 + shf * 64);
#pragma unroll
        for (int j = 0; j < 8; j++) stg1[j] = gp[j];
    }

    auto compute_store = [&](_Float16* __restrict__ C) {
        f32x4 acc[2][8];
#pragma unroll
        for (int rt = 0; rt < 2; rt++)
#pragma unroll
            for (int c = 0; c < 8; c++) acc[rt][c] = (f32x4){0.f, 0.f, 0.f, 0.f};

#pragma unroll
        for (int s = 0; s < 4; s++) {
#pragma unroll
            for (int c = 0; c < 8; c++) {
                f16x8 bw = *(const f16x8*)&ldsW[(c * 16 + mrow) * 136 + s * 32 + quad * 8];
                acc[0][c] = __builtin_amdgcn_mfma_f32_16x16x32_f16(ah[0][s], bw, acc[0][c], 0, 0, 0);
                acc[0][c] = __builtin_amdgcn_mfma_f32_16x16x32_f16(al[0][s], bw, acc[0][c], 0, 0, 0);
                acc[1][c] = __builtin_amdgcn_mfma_f32_16x16x32_f16(ah[1][s], bw, acc[1][c], 0, 0, 0);
                acc[1][c] = __builtin_amdgcn_mfma_f32_16x16x32_f16(al[1][s], bw, acc[1][c], 0, 0, 0);
            }
        }

        // D mapping: col = lane&15, row = quad*4 + reg
#pragma unroll
        for (int rt = 0; rt < 2; rt++)
#pragma unroll
            for (int i = 0; i < 4; i++) {
                int r = rbase + rt * 16 + quad * 4 + i;
                if (r < N) {
                    _Float16* cr = C + (size_t)r * 128 + mrow;
#pragma unroll
                    for (int c = 0; c < 8; c++) cr[c * 16] = (_Float16)acc[rt][c][i];
                }
            }
    };

    compute_store(Cl);

    __syncthreads();   // all waves done reading W0
    {
        float4* d = (float4*)&ldsW[sn * 136 + shf * 64];
#pragma unroll
        for (int j = 0; j < 8; j++) d[j] = stg1[j];
    }
    __syncthreads();

    compute_store(Cr);
}

// ---------------------------------------------------------------------------
// Single-pass bucketing (replaces histB+scanB+passA): per-chunk LDS hist
// gives in-chunk ranks; global cursor atomics (pre-initialized to bk*BCAP by
// prep) reserve space in fixed-capacity padded bucket regions. No global
// scan pass needed.
// ---------------------------------------------------------------------------
__global__ __launch_bounds__(256) void bucketA_kernel(
    const int* __restrict__ ei, int* __restrict__ gcursor,
    int2* __restrict__ staging, int E)
{
    __shared__ int bh[256];
    __shared__ int bbase[256];
    int t = threadIdx.x;
    bh[t] = 0;
    __syncthreads();
    int base = blockIdx.x * CHUNK;
    int srcv[16], dstv[16], rb[16];
#pragma unroll
    for (int j = 0; j < 16; j++) {
        int e = base + t + j * 256;
        if (e < E) {
            int d = ei[E + e];
            srcv[j] = ei[e];
            dstv[j] = d;
            int bk = d >> 8;
            int r = atomicAdd(&bh[bk], 1);
            rb[j] = (r << 8) | bk;
        } else rb[j] = -1;
    }
    __syncthreads();
    if (bh[t]) bbase[t] = atomicAdd(&gcursor[t], bh[t]);
    __syncthreads();
#pragma unroll
    for (int j = 0; j < 16; j++) {
        if (rb[j] >= 0) {
            int bk = rb[j] & 255, r = rb[j] >> 8;
            staging[bbase[bk] + r] = make_int2(srcv[j], dstv[j]);
        }
    }
}

// ---------------------------------------------------------------------------
// Per-bucket counting sort into padded CSR: writes start[] (absolute index
// into the padded sorted_src space) and deg[] per node.
// ---------------------------------------------------------------------------
__global__ __launch_bounds__(256) void passB_kernel(
    const int2* __restrict__ staging, const int* __restrict__ gcursor,
    int* __restrict__ start, int* __restrict__ deg,
    int* __restrict__ sorted_src, int N)
{
    __shared__ int lhist[256], lscan[256], lcur[256];
    int b = blockIdx.x, t = threadIdx.x;
    int r0 = b * BCAP;
    int r1 = gcursor[b];          // final fill cursor for this bucket
    lhist[t] = 0;
    __syncthreads();
    for (int i = r0 + t; i < r1; i += 256) atomicAdd(&lhist[staging[i].y & 255], 1);
    __syncthreads();
    int v = lhist[t];
    lscan[t] = v;
    __syncthreads();
    for (int off = 1; off < 256; off <<= 1) {
        int u = (t >= off) ? lscan[t - off] : 0;
        __syncthreads();
        lscan[t] += u;
        __syncthreads();
    }
    int excl = lscan[t] - v;
    int node = b * NPB + t;
    if (node < N) { start[node] = r0 + excl; deg[node] = v; }
    lcur[t] = excl;
    __syncthreads();
    for (int i = r0 + t; i < r1; i += 256) {
        int2 p = staging[i];
        int rank = atomicAdd(&lcur[p.y & 255], 1);
        sorted_src[r0 + rank] = p.x;
    }
}

// ---------------------------------------------------------------------------
// Fused score+softmax+aggregate.
// One wave per dst node; 16 lanes per edge (f16x8/lane), 4 edges per group.
// Score reduction entirely via DPP (no ds_bpermute in the inner loop).
// H==2 stops after 3 steps: lanes 0-7 = head 0, 8-15 = head 1.
// att pre-scaled by log2(e) -> exp2f. Self-loop = virtual edge 0.
// ---------------------------------------------------------------------------
template <int H, bool BFOUT>
__global__ __launch_bounds__(256) void gat_fused_kernel(
    const _Float16* __restrict__ xl, const _Float16* __restrict__ xr,
    const float* __restrict__ att, const float* __restrict__ bias,
    const int* __restrict__ start, const int* __restrict__ deg,
    const int* __restrict__ sorted_src,
    float* __restrict__ outf, _Float16* __restrict__ oh,
    _Float16* __restrict__ ol, int N)
{
    int node = blockIdx.x * 4 + (threadIdx.x >> 6);
    if (node >= N) return;
    const int lane = threadIdx.x & 63;
    const int g  = lane >> 4;          // edge slot 0..3
    const int hl = lane & 15;          // feature slot: ch [hl*8, hl*8+8)
    const _Float16 NS = (_Float16)NEG_SLOPE;
    const float L2E = 1.44269504f;

    const f16x8 b4 = *(const f16x8*)(xr + (size_t)node * 128 + hl * 8);
    float4 at0 = *(const float4*)(att + hl * 8);
    float4 at1 = *(const float4*)(att + hl * 8 + 4);
#if defined(HAVE_FDOT2)
    f16x2 av0 = {(_Float16)(at0.x * L2E), (_Float16)(at0.y * L2E)};
    f16x2 av1 = {(_Float16)(at0.z * L2E), (_Float16)(at0.w * L2E)};
    f16x2 av2 = {(_Float16)(at1.x * L2E), (_Float16)(at1.y * L2E)};
    f16x2 av3 = {(_Float16)(at1.z * L2E), (_Float16)(at1.w * L2E)};
#else
    f32x8 avf = {at0.x * L2E, at0.y * L2E, at0.z * L2E, at0.w * L2E,
                 at1.x * L2E, at1.y * L2E, at1.z * L2E, at1.w * L2E};
#endif

    auto score = [&](f16x8 a_) -> float {
        f16x8 t = a_ + b4;
        f16x8 u = __builtin_elementwise_max(t, t * NS);
#if defined(HAVE_FDOT2)
        f16x2 u0 = __builtin_shufflevector(u, u, 0, 1);
        f16x2 u1 = __builtin_shufflevector(u, u, 2, 3);
        f16x2 u2 = __builtin_shufflevector(u, u, 4, 5);
        f16x2 u3 = __builtin_shufflevector(u, u, 6, 7);
        return __builtin_amdgcn_fdot2(u0, av0,
               __builtin_amdgcn_fdot2(u1, av1,
               __builtin_amdgcn_fdot2(u2, av2,
               __builtin_amdgcn_fdot2(u3, av3, 0.f, false), false), false), false);
#else
        f32x8 uf = cvt8(u);
        float p = 0.f;
#pragma unroll
        for (int i = 0; i < 8; i++) p += uf[i] * avf[i];
        return p;
#endif
    };

    // 16-lane (or 8-lane for H==2) butterfly reduce, pure DPP.
    auto red = [&](float p) -> float {
        p = dpp_add<0xB1>(p);            // xor1
        p = dpp_add<0x4E>(p);            // xor2
        p = dpp_add<0x141>(p);           // xor4 (row_half_mirror)
        if (H == 1) p = dpp_add<0x140>(p);   // xor8 (row_mirror)
        return p;
    };

    f32x8 acc = {0.f, 0.f, 0.f, 0.f, 0.f, 0.f, 0.f, 0.f};
    float den = 0.f;

    const int s0 = start[node];
    const int M  = deg[node] + 1;      // incl. self-loop at iv==0
    const int Kfull = M >> 2;          // full 4-edge groups
    const int K     = (M + 3) >> 2;

#define GBODY(B) {                                                          \
        int srcv[B]; f16x8 a[B]; float p[B];                                \
        _Pragma("unroll")                                                   \
        for (int j = 0; j < B; j++) {                                       \
            int iv = 4 * (k + j) + g;                                       \
            int ld = sorted_src[s0 + ((iv > 0) ? iv - 1 : 0)];              \
            srcv[j] = (iv == 0) ? node : ld;                                \
        }                                                                   \
        _Pragma("unroll")                                                   \
        for (int j = 0; j < B; j++)                                         \
            a[j] = *(const f16x8*)(xl + (size_t)srcv[j] * 128 + hl * 8);    \
        _Pragma("unroll")                                                   \
        for (int j = 0; j < B; j++) p[j] = score(a[j]);                     \
        _Pragma("unroll")                                                   \
        for (int j = 0; j < B; j++) p[j] = red(p[j]);                       \
        _Pragma("unroll")                                                   \
        for (int j = 0; j < B; j++) {                                       \
            float e = exp2f(p[j]);                                          \
            den += e;                                                       \
            acc = acc + cvt8(a[j]) * e;                                     \
        }                                                                   \
    }

    int k = 0;
    for (; k + 4 <= Kfull; k += 4) GBODY(4)       // 16 edges in flight
    if (k + 2 <= Kfull) { GBODY(2) k += 2; }      // 8 edges
    if (k < Kfull)      { GBODY(1) k += 1; }      // 4 edges
    if (k < K) {                                  // masked tail (<=1 iter)
        int iv = 4 * k + g;
        bool valid = iv < M;                      // uniform within 16-lane group
        int ld = sorted_src[s0 + ((iv > 0) ? iv - 1 : 0)];  // padded region
        int src = (iv == 0) ? node : (valid ? ld : node);
        f16x8 a = *(const f16x8*)(xl + (size_t)src * 128 + hl * 8);
        float p = red(score(a));
        float e = valid ? exp2f(p) : 0.f;
        den += e;
        acc = acc + cvt8(a) * e;
    }
#undef GBODY

    // combine the 4 edge-groups (feature-aligned): masks 16 and 32 only.
    den += __shfl_xor(den, 16, 64);
    den += __shfl_xor(den, 32, 64);
#pragma unroll
    for (int i = 0; i < 8; i++) {
        acc[i] += __shfl_xor(acc[i], 16, 64);
        acc[i] += __shfl_xor(acc[i], 32, 64);
    }

    float inv = 1.0f / den;
    float4 bi0 = *(const float4*)(bias + hl * 8);
    float4 bi1 = *(const float4*)(bias + hl * 8 + 4);
    float o[8];
    o[0] = acc[0] * inv + bi0.x;  o[1] = acc[1] * inv + bi0.y;
    o[2] = acc[2] * inv + bi0.z;  o[3] = acc[3] * inv + bi0.w;
    o[4] = acc[4] * inv + bi1.x;  o[5] = acc[5] * inv + bi1.y;
    o[6] = acc[6] * inv + bi1.z;  o[7] = acc[7] * inv + bi1.w;

    if (lane < 16) {
        if (BFOUT) {   // next layer's A: fp16 hi+lo split
            f16x8 hv, lv;
#pragma unroll
            for (int i = 0; i < 8; i++) {
                _Float16 h = (_Float16)o[i];
                hv[i] = h;
                lv[i] = (_Float16)(o[i] - (float)h);
            }
            *(f16x8*)(oh + (size_t)node * 128 + hl * 8) = hv;
            *(f16x8*)(ol + (size_t)node * 128 + hl * 8) = lv;
        } else {
            *(float4*)(outf + (size_t)node * 128 + hl * 8) =
                make_float4(o[0], o[1], o[2], o[3]);
            *(float4*)(outf + (size_t)node * 128 + hl * 8 + 4) =
                make_float4(o[4], o[5], o[6], o[7]);
        }
    }
}

// ---------------------------------------------------------------------------
extern "C" void kernel_launch(void* const* d_in, const int* in_sizes, int n_in,
                              void* d_out, int out_size, void* d_ws, size_t ws_size,
                              hipStream_t stream)
{
    const float* x    = (const float*)d_in[0];
    const int*   ei   = (const int*)d_in[1];
    const float* Wl1  = (const float*)d_in[3];
    const float* Wr1  = (const float*)d_in[4];
    const float* att1 = (const float*)d_in[5];
    const float* b1   = (const float*)d_in[6];
    const float* Wl2  = (const float*)d_in[7];
    const float* Wr2  = (const float*)d_in[8];
    const float* att2 = (const float*)d_in[9];
    const float* b2   = (const float*)d_in[10];
    float* out = (float*)d_out;

    const int N  = in_sizes[0] / 128;
    const int E  = in_sizes[1] / 2;
    const int NB = (N + NPB - 1) / NPB;

    const size_t nf = (size_t)N * 128;
    _Float16* xlf  = (_Float16*)d_ws;                 // nf fp16 (gather array)
    _Float16* xrf  = xlf + nf;                        // nf fp16
    _Float16* ah   = xrf + nf;                        // nf fp16 (A hi: x, then h)
    _Float16* al   = ah + nf;                         // nf fp16 (A lo)
    _Float16* wt   = al + nf;                         // 4*16384 fp16
    int* gcursor   = (int*)(wt + 4 * 16384);          // 256
    int* start     = gcursor + 256;                   // N
    int* deg       = start + N;                       // N
    size_t stgoff  = ((size_t)(deg + N) + 7) & ~(size_t)7;
    int2* staging  = (int2*)stgoff;                   // NB*BCAP int2 (padded)
    int* sorted_src = (int*)(staging + (size_t)NB * BCAP);  // NB*BCAP + 64 ints

    const int grid_chunk = (E + CHUNK - 1) / CHUNK;
    const int node_grid  = (N + 3) / 4;
    const int gemm_gx    = (N + 127) / 128;
    const int split_grid = (int)((nf / 2 + 255) / 256);

    // ---- prep: W->fp16 transposed, x split, gcursor init ----
    prep_kernel<<<256 + split_grid, 256, 0, stream>>>(
        Wl1, Wr1, Wl2, Wr2, wt, x, ah, al, (int)nf, gcursor);

    // ---- padded-bucket CSR build (shared by both layers) ----
    bucketA_kernel<<<grid_chunk, 256, 0, stream>>>(ei, gcursor, staging, E);
    passB_kernel<<<NB, 256, 0, stream>>>(staging, gcursor, start, deg,
                                         sorted_src, N);

    // ---- Layer 1: heads=2, ch=64 ----
    gemm_f16_kernel<<<gemm_gx, 256, 0, stream>>>(
        ah, al, wt + 0 * 16384, wt + 1 * 16384, xlf, xrf, N);
    gat_fused_kernel<2, true><<<node_grid, 256, 0, stream>>>(
        xlf, xrf, att1, b1, start, deg, sorted_src, nullptr, ah, al, N);

    // ---- Layer 2: heads=1, ch=128 ----
    gemm_f16_kernel<<<gemm_gx, 256, 0, stream>>>(
        ah, al, wt + 2 * 16384, wt + 3 * 16384, xlf, xrf, N);
    gat_fused_kernel<1, false><<<node_grid, 256, 0, stream>>>(
        xlf, xrf, att2, b2, start, deg, sorted_src, out, nullptr, nullptr, N);
}

// Round 5
// 276.841 us; speedup vs baseline: 1.1331x; 1.0347x over previous
//
#include <hip/hip_runtime.h>

#define NEG_SLOPE 0.2f
#define NPB 256          // nodes per dst-bucket (bucket = dst >> 8)
#define CHUNK 4096       // edges per partition block
#define BCAP 5120        // padded bucket capacity (expected fill 4096, +16 sigma)

typedef _Float16 f16x8 __attribute__((ext_vector_type(8)));
typedef _Float16 f16x4 __attribute__((ext_vector_type(4)));
typedef _Float16 f16x2 __attribute__((ext_vector_type(2)));
typedef float    f32x4 __attribute__((ext_vector_type(4)));
typedef float    f32x8 __attribute__((ext_vector_type(8)));

#if defined(__has_builtin)
#if __has_builtin(__builtin_amdgcn_fdot2)
#define HAVE_FDOT2 1
#endif
#endif

__device__ __forceinline__ f32x8 cvt8(f16x8 v) {
    return __builtin_convertvector(v, f32x8);
}

// DPP butterfly add step — pure VALU, no LDS pipe (vs __shfl_xor's ds_bpermute).
// CTRL: 0xB1 = quad_perm(1,0,3,2) (xor1), 0x4E = quad_perm(2,3,0,1) (xor2),
// 0x141 = row_half_mirror (xor4 once quads uniform), 0x140 = row_mirror (xor8
// once 8-groups uniform). CTRL must be a compile-time constant -> template.
template <int CTRL>
__device__ __forceinline__ float dpp_add(float v) {
    int o = __builtin_amdgcn_update_dpp(0, __builtin_bit_cast(int, v),
                                        CTRL, 0xF, 0xF, true);
    return v + __builtin_bit_cast(float, o);
}

// ---------------------------------------------------------------------------
// prep: W transpose->fp16 (blocks 0..255), x fp32->fp16 hi/lo split
// (blocks 256..), gcursor init to bucket bases (block 0).
// ---------------------------------------------------------------------------
__global__ __launch_bounds__(256) void prep_kernel(
    const float* __restrict__ W0, const float* __restrict__ W1,
    const float* __restrict__ W2, const float* __restrict__ W3,
    _Float16* __restrict__ wt,
    const float* __restrict__ x, _Float16* __restrict__ xh,
    _Float16* __restrict__ xlo, int total, int* __restrict__ gcursor)
{
    int t = threadIdx.x;
    if (blockIdx.x < 256) {
        if (blockIdx.x == 0) gcursor[t] = t * BCAP;
        int idx = blockIdx.x * 256 + t;     // 4*128*128
        int m = idx >> 14;
        int k = (idx >> 7) & 127;
        int n = idx & 127;
        const float* W = (m == 0) ? W0 : (m == 1) ? W1 : (m == 2) ? W2 : W3;
        wt[m * 16384 + n * 128 + k] = (_Float16)W[k * 128 + n];
    } else {
        int i = (blockIdx.x - 256) * 256 + t;
        if (i * 2 < total) {
            float2 f = *(const float2*)(x + (size_t)i * 2);
            _Float16 h0 = (_Float16)f.x, h1 = (_Float16)f.y;
            _Float16 l0 = (_Float16)(f.x - (float)h0), l1 = (_Float16)(f.y - (float)h1);
            *(f16x2*)(xh  + (size_t)i * 2) = (f16x2){h0, h1};
            *(f16x2*)(xlo + (size_t)i * 2) = (f16x2){l0, l1};
        }
    }
}

// ---------------------------------------------------------------------------
// fp16 MFMA GEMM, LDS-staged W (34 KB). C = Ah@W + Al@W, fp32 acc.
// Two-launch form (blockIdx.y selects W / output) — no mid-kernel store
// drain (the merged one-launch variant stalled 124us on vmcnt(0) drains).
// ---------------------------------------------------------------------------
__global__ __launch_bounds__(256) void gemm_f16_kernel(
    const _Float16* __restrict__ Ahi, const _Float16* __restrict__ Alo,
    const _Float16* __restrict__ Wt0, const _Float16* __restrict__ Wt1,
    _Float16* __restrict__ Cl, _Float16* __restrict__ Cr, int N)
{
    const _Float16* Wt = blockIdx.y ? Wt1 : Wt0;
    _Float16* C = blockIdx.y ? Cr : Cl;

    __shared__ _Float16 ldsW[128 * 136];   // row stride 272 B

    const int tid = threadIdx.x;
    const int wave = tid >> 6;
    const int lane = tid & 63;
    const int mrow = lane & 15;
    const int quad = lane >> 4;
    const int rbase = blockIdx.x * 128 + wave * 32;

    // staging loads first (latency overlaps A loads)
    const int sn = tid >> 1, shf = tid & 1;
    float4 stg[8];
    {
        const float4* g = (const float4*)(Wt + sn * 128 + shf * 64);
#pragma unroll
        for (int j = 0; j < 8; j++) stg[j] = g[j];
    }

    f16x8 ah[2][4], al[2][4];
#pragma unroll
    for (int rt = 0; rt < 2; rt++) {
        int r = rbase + rt * 16 + mrow;
        if (r > N - 1) r = N - 1;
        const _Float16* pa = Ahi + (size_t)r * 128 + quad * 8;
        const _Float16* pl = Alo + (size_t)r * 128 + quad * 8;
#pragma unroll
        for (int s = 0; s < 4; s++) {
            ah[rt][s] = *(const f16x8*)(pa + s * 32);
            al[rt][s] = *(const f16x8*)(pl + s * 32);
        }
    }

    {
        float4* d = (float4*)&ldsW[sn * 136 + shf * 64];
#pragma unroll
        for (int j = 0; j < 8; j++) d[j] = stg[j];
    }

    f32x4 acc[2][8];
#pragma unroll
    for (int rt = 0; rt < 2; rt++)
#pragma unroll
        for (int c = 0; c < 8; c++) acc[rt][c] = (f32x4){0.f, 0.f, 0.f, 0.f};

    __syncthreads();

#pragma unroll
    for (int s = 0; s < 4; s++) {
#pragma unroll
        for (int c = 0; c < 8; c++) {
            f16x8 bw = *(const f16x8*)&ldsW[(c * 16 + mrow) * 136 + s * 32 + quad * 8];
            acc[0][c] = __builtin_amdgcn_mfma_f32_16x16x32_f16(ah[0][s], bw, acc[0][c], 0, 0, 0);
            acc[0][c] = __builtin_amdgcn_mfma_f32_16x16x32_f16(al[0][s], bw, acc[0][c], 0, 0, 0);
            acc[1][c] = __builtin_amdgcn_mfma_f32_16x16x32_f16(ah[1][s], bw, acc[1][c], 0, 0, 0);
            acc[1][c] = __builtin_amdgcn_mfma_f32_16x16x32_f16(al[1][s], bw, acc[1][c], 0, 0, 0);
        }
    }

    // D mapping: col = lane&15, row = quad*4 + reg
#pragma unroll
    for (int rt = 0; rt < 2; rt++)
#pragma unroll
        for (int i = 0; i < 4; i++) {
            int r = rbase + rt * 16 + quad * 4 + i;
            if (r < N) {
                _Float16* cr = C + (size_t)r * 128 + mrow;
#pragma unroll
                for (int c = 0; c < 8; c++) cr[c * 16] = (_Float16)acc[rt][c][i];
            }
        }
}

// ---------------------------------------------------------------------------
// Single-pass bucketing: per-chunk LDS hist gives in-chunk ranks; global
// cursor atomics (pre-initialized to bk*BCAP by prep) reserve space in
// fixed-capacity padded bucket regions.
// ---------------------------------------------------------------------------
__global__ __launch_bounds__(256) void bucketA_kernel(
    const int* __restrict__ ei, int* __restrict__ gcursor,
    int2* __restrict__ staging, int E)
{
    __shared__ int bh[256];
    __shared__ int bbase[256];
    int t = threadIdx.x;
    bh[t] = 0;
    __syncthreads();
    int base = blockIdx.x * CHUNK;
    int srcv[16], dstv[16], rb[16];
#pragma unroll
    for (int j = 0; j < 16; j++) {
        int e = base + t + j * 256;
        if (e < E) {
            int d = ei[E + e];
            srcv[j] = ei[e];
            dstv[j] = d;
            int bk = d >> 8;
            int r = atomicAdd(&bh[bk], 1);
            rb[j] = (r << 8) | bk;
        } else rb[j] = -1;
    }
    __syncthreads();
    if (bh[t]) bbase[t] = atomicAdd(&gcursor[t], bh[t]);
    __syncthreads();
#pragma unroll
    for (int j = 0; j < 16; j++) {
        if (rb[j] >= 0) {
            int bk = rb[j] & 255, r = rb[j] >> 8;
            staging[bbase[bk] + r] = make_int2(srcv[j], dstv[j]);
        }
    }
}

// ---------------------------------------------------------------------------
// Per-bucket counting sort into padded CSR: writes start[] (absolute index
// into the padded sorted_src space) and deg[] per node.
// ---------------------------------------------------------------------------
__global__ __launch_bounds__(256) void passB_kernel(
    const int2* __restrict__ staging, const int* __restrict__ gcursor,
    int* __restrict__ start, int* __restrict__ deg,
    int* __restrict__ sorted_src, int N)
{
    __shared__ int lhist[256], lscan[256], lcur[256];
    int b = blockIdx.x, t = threadIdx.x;
    int r0 = b * BCAP;
    int r1 = gcursor[b];          // final fill cursor for this bucket
    lhist[t] = 0;
    __syncthreads();
    for (int i = r0 + t; i < r1; i += 256) atomicAdd(&lhist[staging[i].y & 255], 1);
    __syncthreads();
    int v = lhist[t];
    lscan[t] = v;
    __syncthreads();
    for (int off = 1; off < 256; off <<= 1) {
        int u = (t >= off) ? lscan[t - off] : 0;
        __syncthreads();
        lscan[t] += u;
        __syncthreads();
    }
    int excl = lscan[t] - v;
    int node = b * NPB + t;
    if (node < N) { start[node] = r0 + excl; deg[node] = v; }
    lcur[t] = excl;
    __syncthreads();
    for (int i = r0 + t; i < r1; i += 256) {
        int2 p = staging[i];
        int rank = atomicAdd(&lcur[p.y & 255], 1);
        sorted_src[r0 + rank] = p.x;
    }
}

// ---------------------------------------------------------------------------
// Fused score+softmax+aggregate.
// TWO nodes per wave (lockstep over max(K0,K1) groups, per-node masking):
// the 2nd node's idx/gather chains overlap the 1st's compute, and per-wave
// fixed overhead amortizes 2x. One batch of software pipelining keeps 8
// gathers in flight during compute. 16 lanes per edge (f16x8/lane), 4 edge
// slots per group. Score reduction via DPP; H==2 stops at the 8-lane
// boundary (lanes 0-7 = head 0, 8-15 = head 1). att pre-scaled by log2(e)
// -> exp2f. Self-loop = virtual edge 0. Lanes 0-15 store node0, 16-31 node1.
// ---------------------------------------------------------------------------
template <int H, bool BFOUT>
__global__ __launch_bounds__(256) void gat_fused_kernel(
    const _Float16* __restrict__ xl, const _Float16* __restrict__ xr,
    const float* __restrict__ att, const float* __restrict__ bias,
    const int* __restrict__ start, const int* __restrict__ deg,
    const int* __restrict__ sorted_src,
    float* __restrict__ outf, _Float16* __restrict__ oh,
    _Float16* __restrict__ ol, int N)
{
    const int wid = threadIdx.x >> 6;
    const int n0 = blockIdx.x * 8 + wid * 2;
    if (n0 >= N) return;
    const bool has1 = (n0 + 1) < N;
    const int n1 = has1 ? n0 + 1 : n0;
    const int lane = threadIdx.x & 63;
    const int g  = lane >> 4;          // edge slot 0..3 within a group
    const int hl = lane & 15;          // feature slot: ch [hl*8, hl*8+8)
    const _Float16 NS = (_Float16)NEG_SLOPE;
    const float L2E = 1.44269504f;

    const f16x8 b40 = *(const f16x8*)(xr + (size_t)n0 * 128 + hl * 8);
    const f16x8 b41 = *(const f16x8*)(xr + (size_t)n1 * 128 + hl * 8);
    float4 at0 = *(const float4*)(att + hl * 8);
    float4 at1 = *(const float4*)(att + hl * 8 + 4);
#if defined(HAVE_FDOT2)
    f16x2 av0 = {(_Float16)(at0.x * L2E), (_Float16)(at0.y * L2E)};
    f16x2 av1 = {(_Float16)(at0.z * L2E), (_Float16)(at0.w * L2E)};
    f16x2 av2 = {(_Float16)(at1.x * L2E), (_Float16)(at1.y * L2E)};
    f16x2 av3 = {(_Float16)(at1.z * L2E), (_Float16)(at1.w * L2E)};
#else
    f32x8 avf = {at0.x * L2E, at0.y * L2E, at0.z * L2E, at0.w * L2E,
                 at1.x * L2E, at1.y * L2E, at1.z * L2E, at1.w * L2E};
#endif

    auto score = [&](f16x8 a_, f16x8 b4_) -> float {
        f16x8 t = a_ + b4_;
        f16x8 u = __builtin_elementwise_max(t, t * NS);
#if defined(HAVE_FDOT2)
        f16x2 u0 = __builtin_shufflevector(u, u, 0, 1);
        f16x2 u1 = __builtin_shufflevector(u, u, 2, 3);
        f16x2 u2 = __builtin_shufflevector(u, u, 4, 5);
        f16x2 u3 = __builtin_shufflevector(u, u, 6, 7);
        return __builtin_amdgcn_fdot2(u0, av0,
               __builtin_amdgcn_fdot2(u1, av1,
               __builtin_amdgcn_fdot2(u2, av2,
               __builtin_amdgcn_fdot2(u3, av3, 0.f, false), false), false), false);
#else
        f32x8 uf = cvt8(u);
        float p = 0.f;
#pragma unroll
        for (int i = 0; i < 8; i++) p += uf[i] * avf[i];
        return p;
#endif
    };

    // 16-lane (or 8-lane for H==2) butterfly reduce, pure DPP.
    auto red = [&](float p) -> float {
        p = dpp_add<0xB1>(p);            // xor1
        p = dpp_add<0x4E>(p);            // xor2
        p = dpp_add<0x141>(p);           // xor4 (row_half_mirror)
        if (H == 1) p = dpp_add<0x140>(p);   // xor8 (row_mirror)
        return p;
    };

    const int s00 = start[n0];
    const int M0  = deg[n0] + 1;       // incl. self-loop at iv==0
    const int s01 = start[n1];
    const int M1  = deg[n1] + 1;
    const int Mmax = (M0 > M1) ? M0 : M1;
    const int K   = (Mmax + 3) >> 2;   // lockstep group count
    const int KK  = (K + 1) & ~1;      // rounded up to pipeline pairs

    // masked group load: invalid slots clamp to the node's own row (e -> 0)
    auto ldone = [&](int kk, int s0_, int M_, int nn) -> f16x8 {
        int iv = 4 * kk + g;
        int pos = s0_ + ((iv > 0) ? iv - 1 : 0);  // stays in padded bucket region
        int ld = sorted_src[pos];
        int src = (iv == 0 || iv >= M_) ? nn : ld;
        return *(const f16x8*)(xl + (size_t)src * 128 + hl * 8);
    };

    f32x8 acc0 = {0.f, 0.f, 0.f, 0.f, 0.f, 0.f, 0.f, 0.f};
    f32x8 acc1 = {0.f, 0.f, 0.f, 0.f, 0.f, 0.f, 0.f, 0.f};
    float den0 = 0.f, den1 = 0.f;

    auto cone = [&](int kk, f16x8 a, f16x8 b4_, int M_, float& den_, f32x8& acc_) {
        float p = red(score(a, b4_));
        float e = (4 * kk + g < M_) ? exp2f(p) : 0.f;
        den_ += e;
#pragma unroll
        for (int i = 0; i < 8; i++)
            acc_[i] = fmaf((float)a[i], e, acc_[i]);   // v_fma_mix
    };

    // software pipeline, 2 groups x 2 nodes per stage (8 gathers in flight)
    f16x8 c00 = ldone(0, s00, M0, n0);
    f16x8 c01 = ldone(0, s01, M1, n1);
    f16x8 c10 = ldone(1, s00, M0, n0);
    f16x8 c11 = ldone(1, s01, M1, n1);
    int k = 2;
    for (; k < KK; k += 2) {
        f16x8 d00 = ldone(k,     s00, M0, n0);
        f16x8 d01 = ldone(k,     s01, M1, n1);
        f16x8 d10 = ldone(k + 1, s00, M0, n0);
        f16x8 d11 = ldone(k + 1, s01, M1, n1);
        cone(k - 2, c00, b40, M0, den0, acc0);
        cone(k - 2, c01, b41, M1, den1, acc1);
        cone(k - 1, c10, b40, M0, den0, acc0);
        cone(k - 1, c11, b41, M1, den1, acc1);
        c00 = d00; c01 = d01; c10 = d10; c11 = d11;
    }
    cone(KK - 2, c00, b40, M0, den0, acc0);
    cone(KK - 2, c01, b41, M1, den1, acc1);
    cone(KK - 1, c10, b40, M0, den0, acc0);
    cone(KK - 1, c11, b41, M1, den1, acc1);

    // combine the 4 edge-groups (feature-aligned): masks 16 and 32 only.
    den0 += __shfl_xor(den0, 16, 64);
    den0 += __shfl_xor(den0, 32, 64);
    den1 += __shfl_xor(den1, 16, 64);
    den1 += __shfl_xor(den1, 32, 64);
#pragma unroll
    for (int i = 0; i < 8; i++) {
        acc0[i] += __shfl_xor(acc0[i], 16, 64);
        acc0[i] += __shfl_xor(acc0[i], 32, 64);
        acc1[i] += __shfl_xor(acc1[i], 16, 64);
        acc1[i] += __shfl_xor(acc1[i], 32, 64);
    }

    // lanes 0-15 store node0, lanes 16-31 store node1 (parallel epilogue)
    const int which = lane >> 4;
    if (which == 0 || (which == 1 && has1)) {
        float inv = 1.0f / (which == 0 ? den0 : den1);
        int nodeo = (which == 0) ? n0 : n1;
        float4 bi0 = *(const float4*)(bias + hl * 8);
        float4 bi1 = *(const float4*)(bias + hl * 8 + 4);
        float o[8];
#pragma unroll
        for (int i = 0; i < 8; i++) {
            float a = (which == 0) ? acc0[i] : acc1[i];
            float b = (i < 4) ? ((i == 0) ? bi0.x : (i == 1) ? bi0.y : (i == 2) ? bi0.z : bi0.w)
                              : ((i == 4) ? bi1.x : (i == 5) ? bi1.y : (i == 6) ? bi1.z : bi1.w);
            o[i] = a * inv + b;
        }
        if (BFOUT) {   // next layer's A: fp16 hi+lo split
            f16x8 hv, lv;
#pragma unroll
            for (int i = 0; i < 8; i++) {
                _Float16 h = (_Float16)o[i];
                hv[i] = h;
                lv[i] = (_Float16)(o[i] - (float)h);
            }
            *(f16x8*)(oh + (size_t)nodeo * 128 + hl * 8) = hv;
            *(f16x8*)(ol + (size_t)nodeo * 128 + hl * 8) = lv;
        } else {
            *(float4*)(outf + (size_t)nodeo * 128 + hl * 8) =
                make_float4(o[0], o[1], o[2], o[3]);
            *(float4*)(outf + (size_t)nodeo * 128 + hl * 8 + 4) =
                make_float4(o[4], o[5], o[6], o[7]);
        }
    }
}

// ---------------------------------------------------------------------------
extern "C" void kernel_launch(void* const* d_in, const int* in_sizes, int n_in,
                              void* d_out, int out_size, void* d_ws, size_t ws_size,
                              hipStream_t stream)
{
    const float* x    = (const float*)d_in[0];
    const int*   ei   = (const int*)d_in[1];
    const float* Wl1  = (const float*)d_in[3];
    const float* Wr1  = (const float*)d_in[4];
    const float* att1 = (const float*)d_in[5];
    const float* b1   = (const float*)d_in[6];
    const float* Wl2  = (const float*)d_in[7];
    const float* Wr2  = (const float*)d_in[8];
    const float* att2 = (const float*)d_in[9];
    const float* b2   = (const float*)d_in[10];
    float* out = (float*)d_out;

    const int N  = in_sizes[0] / 128;
    const int E  = in_sizes[1] / 2;
    const int NB = (N + NPB - 1) / NPB;

    const size_t nf = (size_t)N * 128;
    _Float16* xlf  = (_Float16*)d_ws;                 // nf fp16 (gather array)
    _Float16* xrf  = xlf + nf;                        // nf fp16
    _Float16* ah   = xrf + nf;                        // nf fp16 (A hi: x, then h)
    _Float16* al   = ah + nf;                         // nf fp16 (A lo)
    _Float16* wt   = al + nf;                         // 4*16384 fp16
    int* gcursor   = (int*)(wt + 4 * 16384);          // 256
    int* start     = gcursor + 256;                   // N
    int* deg       = start + N;                       // N
    size_t stgoff  = ((size_t)(deg + N) + 7) & ~(size_t)7;
    int2* staging  = (int2*)stgoff;                   // NB*BCAP int2 (padded)
    int* sorted_src = (int*)(staging + (size_t)NB * BCAP);  // NB*BCAP + 64 ints

    const int grid_chunk = (E + CHUNK - 1) / CHUNK;
    const int node_grid  = (N + 7) / 8;               // 8 nodes per block (2/wave)
    const int gemm_gx    = (N + 127) / 128;
    const int split_grid = (int)((nf / 2 + 255) / 256);

    // ---- prep: W->fp16 transposed, x split, gcursor init ----
    prep_kernel<<<256 + split_grid, 256, 0, stream>>>(
        Wl1, Wr1, Wl2, Wr2, wt, x, ah, al, (int)nf, gcursor);

    // ---- padded-bucket CSR build (shared by both layers) ----
    bucketA_kernel<<<grid_chunk, 256, 0, stream>>>(ei, gcursor, staging, E);
    passB_kernel<<<NB, 256, 0, stream>>>(staging, gcursor, start, deg,
                                         sorted_src, N);

    // ---- Layer 1: heads=2, ch=64 ----
    gemm_f16_kernel<<<dim3(gemm_gx, 2), 256, 0, stream>>>(
        ah, al, wt + 0 * 16384, wt + 1 * 16384, xlf, xrf, N);
    gat_fused_kernel<2, true><<<node_grid, 256, 0, stream>>>(
        xlf, xrf, att1, b1, start, deg, sorted_src, nullptr, ah, al, N);

    // ---- Layer 2: heads=1, ch=128 ----
    gemm_f16_kernel<<<dim3(gemm_gx, 2), 256, 0, stream>>>(
        ah, al, wt + 2 * 16384, wt + 3 * 16384, xlf, xrf, N);
    gat_fused_kernel<1, false><<<node_grid, 256, 0, stream>>>(
        xlf, xrf, att2, b2, start, deg, sorted_src, out, nullptr, nullptr, N);
}

// Round 6
// 265.233 us; speedup vs baseline: 1.1827x; 1.0438x over previous
//
#include <hip/hip_runtime.h>

#define NEG_SLOPE 0.2f
#define NPB 256          // nodes per dst-bucket (bucket = dst >> 8)
#define CHUNK 4096       // edges per partition block
#define BCAP 5120        // padded bucket capacity (expected fill 4096, +16 sigma)

typedef _Float16 f16x8 __attribute__((ext_vector_type(8)));
typedef _Float16 f16x4 __attribute__((ext_vector_type(4)));
typedef _Float16 f16x2 __attribute__((ext_vector_type(2)));
typedef float    f32x4 __attribute__((ext_vector_type(4)));
typedef float    f32x8 __attribute__((ext_vector_type(8)));

#if defined(__has_builtin)
#if __has_builtin(__builtin_amdgcn_fdot2)
#define HAVE_FDOT2 1
#endif
#endif

__device__ __forceinline__ f32x8 cvt8(f16x8 v) {
    return __builtin_convertvector(v, f32x8);
}

// DPP butterfly add step — pure VALU, no LDS pipe (vs __shfl_xor's ds_bpermute).
// CTRL: 0xB1 = quad_perm(1,0,3,2) (xor1), 0x4E = quad_perm(2,3,0,1) (xor2),
// 0x141 = row_half_mirror (xor4 once quads uniform), 0x140 = row_mirror (xor8
// once 8-groups uniform). CTRL must be a compile-time constant -> template.
template <int CTRL>
__device__ __forceinline__ float dpp_add(float v) {
    int o = __builtin_amdgcn_update_dpp(0, __builtin_bit_cast(int, v),
                                        CTRL, 0xF, 0xF, true);
    return v + __builtin_bit_cast(float, o);
}

// ---------------------------------------------------------------------------
// K1: merged prep + bucketing.
//   blocks [0, B0)        : chunk bucketing with LDS counting-sort so the
//                           staging flush is coalesced per-bucket runs
//                           (was: 800k isolated 8B scatters).
//   blocks [B0, B0+256)   : W transpose -> fp16
//   blocks [B0+256, ...)  : x fp32 -> fp16 hi/lo split
// gcursor must be zeroed before launch (hipMemsetAsync); reservation adds
// the bk*BCAP base so no cross-block init ordering is needed.
// ---------------------------------------------------------------------------
__global__ __launch_bounds__(256) void k1_prep_bucket_kernel(
    const float* __restrict__ W0, const float* __restrict__ W1,
    const float* __restrict__ W2, const float* __restrict__ W3,
    _Float16* __restrict__ wt,
    const float* __restrict__ x, _Float16* __restrict__ xh,
    _Float16* __restrict__ xlo, int total,
    const int* __restrict__ ei, int* __restrict__ gcursor,
    int2* __restrict__ staging, int E, int B0)
{
    __shared__ int2 pairs[CHUNK];          // 32 KB
    __shared__ int bh[256], bbase[256], exb[256], scn[256];
    int t = threadIdx.x;
    int bid = blockIdx.x;

    if (bid < B0) {
        // ---- bucket one chunk of edges ----
        bh[t] = 0;
        __syncthreads();
        int base = bid * CHUNK;
        int srcv[16], dstv[16], rb[16];
#pragma unroll
        for (int j = 0; j < 16; j++) {
            int e = base + t + j * 256;
            if (e < E) {
                int d = ei[E + e];
                srcv[j] = ei[e];
                dstv[j] = d;
                int bk = d >> 8;
                int r = atomicAdd(&bh[bk], 1);
                rb[j] = (r << 8) | bk;
            } else rb[j] = -1;
        }
        __syncthreads();
        // inclusive scan of bh into scn
        int v = bh[t];
        scn[t] = v;
        __syncthreads();
        for (int off = 1; off < 256; off <<= 1) {
            int u = (t >= off) ? scn[t - off] : 0;
            __syncthreads();
            scn[t] += u;
            __syncthreads();
        }
        int ex = scn[t] - v;
        int tot = scn[255];
        exb[t] = ex;
        if (v) bbase[t] = t * BCAP + atomicAdd(&gcursor[t], v);
        __syncthreads();
        // scatter pairs into LDS, bucket-sorted within the chunk
#pragma unroll
        for (int j = 0; j < 16; j++) {
            if (rb[j] >= 0) {
                int bk = rb[j] & 255, r = rb[j] >> 8;
                pairs[exb[bk] + r] = make_int2(srcv[j], dstv[j]);
            }
        }
        __syncthreads();
        // coalesced flush: consecutive i -> same-bucket runs (avg ~16 pairs)
        for (int i = t; i < tot; i += 256) {
            int2 p = pairs[i];
            int bk = p.y >> 8;
            staging[bbase[bk] + (i - exb[bk])] = p;
        }
    } else if (bid < B0 + 256) {
        // ---- W transpose -> fp16 ----
        int idx = (bid - B0) * 256 + t;     // 4*128*128
        int m = idx >> 14;
        int k = (idx >> 7) & 127;
        int n = idx & 127;
        const float* W = (m == 0) ? W0 : (m == 1) ? W1 : (m == 2) ? W2 : W3;
        wt[m * 16384 + n * 128 + k] = (_Float16)W[k * 128 + n];
    } else {
        // ---- x -> fp16 hi/lo split ----
        int i = (bid - B0 - 256) * 256 + t;
        if (i * 2 < total) {
            float2 f = *(const float2*)(x + (size_t)i * 2);
            _Float16 h0 = (_Float16)f.x, h1 = (_Float16)f.y;
            _Float16 l0 = (_Float16)(f.x - (float)h0), l1 = (_Float16)(f.y - (float)h1);
            *(f16x2*)(xh  + (size_t)i * 2) = (f16x2){h0, h1};
            *(f16x2*)(xlo + (size_t)i * 2) = (f16x2){l0, l1};
        }
    }
}

// ---------------------------------------------------------------------------
// fp16 MFMA GEMM block body, LDS-staged W (34 KB). C = Ah@W + Al@W, fp32 acc.
// ---------------------------------------------------------------------------
__device__ __forceinline__ void gemm_body(
    const _Float16* __restrict__ Ahi, const _Float16* __restrict__ Alo,
    const _Float16* __restrict__ Wt, _Float16* __restrict__ C, int N,
    int bx, _Float16* ldsW)
{
    const int tid = threadIdx.x;
    const int wave = tid >> 6;
    const int lane = tid & 63;
    const int mrow = lane & 15;
    const int quad = lane >> 4;
    const int rbase = bx * 128 + wave * 32;

    // staging loads first (latency overlaps A loads)
    const int sn = tid >> 1, shf = tid & 1;
    float4 stg[8];
    {
        const float4* g = (const float4*)(Wt + sn * 128 + shf * 64);
#pragma unroll
        for (int j = 0; j < 8; j++) stg[j] = g[j];
    }

    f16x8 ah[2][4], al[2][4];
#pragma unroll
    for (int rt = 0; rt < 2; rt++) {
        int r = rbase + rt * 16 + mrow;
        if (r > N - 1) r = N - 1;
        const _Float16* pa = Ahi + (size_t)r * 128 + quad * 8;
        const _Float16* pl = Alo + (size_t)r * 128 + quad * 8;
#pragma unroll
        for (int s = 0; s < 4; s++) {
            ah[rt][s] = *(const f16x8*)(pa + s * 32);
            al[rt][s] = *(const f16x8*)(pl + s * 32);
        }
    }

    {
        float4* d = (float4*)&ldsW[sn * 136 + shf * 64];
#pragma unroll
        for (int j = 0; j < 8; j++) d[j] = stg[j];
    }

    f32x4 acc[2][8];
#pragma unroll
    for (int rt = 0; rt < 2; rt++)
#pragma unroll
        for (int c = 0; c < 8; c++) acc[rt][c] = (f32x4){0.f, 0.f, 0.f, 0.f};

    __syncthreads();

#pragma unroll
    for (int s = 0; s < 4; s++) {
#pragma unroll
        for (int c = 0; c < 8; c++) {
            f16x8 bw = *(const f16x8*)&ldsW[(c * 16 + mrow) * 136 + s * 32 + quad * 8];
            acc[0][c] = __builtin_amdgcn_mfma_f32_16x16x32_f16(ah[0][s], bw, acc[0][c], 0, 0, 0);
            acc[0][c] = __builtin_amdgcn_mfma_f32_16x16x32_f16(al[0][s], bw, acc[0][c], 0, 0, 0);
            acc[1][c] = __builtin_amdgcn_mfma_f32_16x16x32_f16(ah[1][s], bw, acc[1][c], 0, 0, 0);
            acc[1][c] = __builtin_amdgcn_mfma_f32_16x16x32_f16(al[1][s], bw, acc[1][c], 0, 0, 0);
        }
    }

    // D mapping: col = lane&15, row = quad*4 + reg
#pragma unroll
    for (int rt = 0; rt < 2; rt++)
#pragma unroll
        for (int i = 0; i < 4; i++) {
            int r = rbase + rt * 16 + quad * 4 + i;
            if (r < N) {
                _Float16* cr = C + (size_t)r * 128 + mrow;
#pragma unroll
                for (int c = 0; c < 8; c++) cr[c * 16] = (_Float16)acc[rt][c][i];
            }
        }
}

// standalone two-dispatch-style GEMM (layer 2): blockIdx.y selects W/output
__global__ __launch_bounds__(256) void gemm_f16_kernel(
    const _Float16* __restrict__ Ahi, const _Float16* __restrict__ Alo,
    const _Float16* __restrict__ Wt0, const _Float16* __restrict__ Wt1,
    _Float16* __restrict__ Cl, _Float16* __restrict__ Cr, int N)
{
    __shared__ _Float16 ldsW[128 * 136];
    gemm_body(Ahi, Alo, blockIdx.y ? Wt1 : Wt0, blockIdx.y ? Cr : Cl, N,
              blockIdx.x, ldsW);
}

// ---------------------------------------------------------------------------
// K2: merged per-bucket counting sort (passB) + layer-1 GEMM (both halves).
//   blocks [0, NB)                 : counting sort -> start/deg/sorted_src
//   blocks [NB, NB+gx)             : gemm y=0 (Cl)
//   blocks [NB+gx, NB+2*gx)        : gemm y=1 (Cr)
// All parts depend only on K1. LDS aliased (gemm 34.8KB / sort 3KB).
// ---------------------------------------------------------------------------
__global__ __launch_bounds__(256) void k2_sort_gemm_kernel(
    const int2* __restrict__ staging, const int* __restrict__ gcursor,
    int* __restrict__ start, int* __restrict__ deg,
    int* __restrict__ sorted_src, int N, int NBv,
    const _Float16* __restrict__ Ahi, const _Float16* __restrict__ Alo,
    const _Float16* __restrict__ Wt0, const _Float16* __restrict__ Wt1,
    _Float16* __restrict__ Cl, _Float16* __restrict__ Cr, int gx)
{
    __shared__ _Float16 ldsW[128 * 136];
    int bx = blockIdx.x;
    if (bx < NBv) {
        int* lhist = (int*)ldsW;
        int* lscan = lhist + 256;
        int* lcur  = lhist + 512;
        int b = bx, t = threadIdx.x;
        int r0 = b * BCAP;
        int r1 = r0 + gcursor[b];     // final fill for this bucket
        lhist[t] = 0;
        __syncthreads();
        for (int i = r0 + t; i < r1; i += 256) atomicAdd(&lhist[staging[i].y & 255], 1);
        __syncthreads();
        int v = lhist[t];
        lscan[t] = v;
        __syncthreads();
        for (int off = 1; off < 256; off <<= 1) {
            int u = (t >= off) ? lscan[t - off] : 0;
            __syncthreads();
            lscan[t] += u;
            __syncthreads();
        }
        int excl = lscan[t] - v;
        int node = b * NPB + t;
        if (node < N) { start[node] = r0 + excl; deg[node] = v; }
        lcur[t] = excl;
        __syncthreads();
        for (int i = r0 + t; i < r1; i += 256) {
            int2 p = staging[i];
            int rank = atomicAdd(&lcur[p.y & 255], 1);
            sorted_src[r0 + rank] = p.x;
        }
    } else {
        int gb = bx - NBv;
        int y = (gb >= gx) ? 1 : 0;
        int gxi = y ? gb - gx : gb;
        gemm_body(Ahi, Alo, y ? Wt1 : Wt0, y ? Cr : Cl, N, gxi, ldsW);
    }
}

// ---------------------------------------------------------------------------
// Fused score+softmax+aggregate.
// TWO nodes per wave, lockstep over max(K0,K1) groups with per-node masking.
// THREE-stage software pipeline: indices for step k+2 and rows for step k+1
// are in flight while computing step k — breaks the serial idx->gather chain.
// 16 lanes per edge (f16x8/lane), 4 edge slots per group. Score reduction
// via DPP; H==2 stops at the 8-lane boundary (lanes 0-7 = head 0, 8-15 =
// head 1). att pre-scaled by log2(e) -> exp2f. Self-loop = virtual edge 0.
// Lanes 0-15 store node0, 16-31 node1.
// ---------------------------------------------------------------------------
template <int H, bool BFOUT>
__global__ __launch_bounds__(256) void gat_fused_kernel(
    const _Float16* __restrict__ xl, const _Float16* __restrict__ xr,
    const float* __restrict__ att, const float* __restrict__ bias,
    const int* __restrict__ start, const int* __restrict__ deg,
    const int* __restrict__ sorted_src,
    float* __restrict__ outf, _Float16* __restrict__ oh,
    _Float16* __restrict__ ol, int N)
{
    const int wid = threadIdx.x >> 6;
    const int n0 = blockIdx.x * 8 + wid * 2;
    if (n0 >= N) return;
    const bool has1 = (n0 + 1) < N;
    const int n1 = has1 ? n0 + 1 : n0;
    const int lane = threadIdx.x & 63;
    const int g  = lane >> 4;          // edge slot 0..3 within a group
    const int hl = lane & 15;          // feature slot: ch [hl*8, hl*8+8)
    const _Float16 NS = (_Float16)NEG_SLOPE;
    const float L2E = 1.44269504f;

    const f16x8 b40 = *(const f16x8*)(xr + (size_t)n0 * 128 + hl * 8);
    const f16x8 b41 = *(const f16x8*)(xr + (size_t)n1 * 128 + hl * 8);
    float4 at0 = *(const float4*)(att + hl * 8);
    float4 at1 = *(const float4*)(att + hl * 8 + 4);
#if defined(HAVE_FDOT2)
    f16x2 av0 = {(_Float16)(at0.x * L2E), (_Float16)(at0.y * L2E)};
    f16x2 av1 = {(_Float16)(at0.z * L2E), (_Float16)(at0.w * L2E)};
    f16x2 av2 = {(_Float16)(at1.x * L2E), (_Float16)(at1.y * L2E)};
    f16x2 av3 = {(_Float16)(at1.z * L2E), (_Float16)(at1.w * L2E)};
#else
    f32x8 avf = {at0.x * L2E, at0.y * L2E, at0.z * L2E, at0.w * L2E,
                 at1.x * L2E, at1.y * L2E, at1.z * L2E, at1.w * L2E};
#endif

    auto score = [&](f16x8 a_, f16x8 b4_) -> float {
        f16x8 t = a_ + b4_;
        f16x8 u = __builtin_elementwise_max(t, t * NS);
#if defined(HAVE_FDOT2)
        f16x2 u0 = __builtin_shufflevector(u, u, 0, 1);
        f16x2 u1 = __builtin_shufflevector(u, u, 2, 3);
        f16x2 u2 = __builtin_shufflevector(u, u, 4, 5);
        f16x2 u3 = __builtin_shufflevector(u, u, 6, 7);
        return __builtin_amdgcn_fdot2(u0, av0,
               __builtin_amdgcn_fdot2(u1, av1,
               __builtin_amdgcn_fdot2(u2, av2,
               __builtin_amdgcn_fdot2(u3, av3, 0.f, false), false), false), false);
#else
        f32x8 uf = cvt8(u);
        float p = 0.f;
#pragma unroll
        for (int i = 0; i < 8; i++) p += uf[i] * avf[i];
        return p;
#endif
    };

    // 16-lane (or 8-lane for H==2) butterfly reduce, pure DPP.
    auto red = [&](float p) -> float {
        p = dpp_add<0xB1>(p);            // xor1
        p = dpp_add<0x4E>(p);            // xor2
        p = dpp_add<0x141>(p);           // xor4 (row_half_mirror)
        if (H == 1) p = dpp_add<0x140>(p);   // xor8 (row_mirror)
        return p;
    };

    const int s00 = start[n0];
    const int M0  = deg[n0] + 1;       // incl. self-loop at iv==0
    const int s01 = start[n1];
    const int M1  = deg[n1] + 1;
    const int Mmax = (M0 > M1) ? M0 : M1;
    const int K   = (Mmax + 3) >> 2;   // lockstep group count
    const int KK  = (K + 1) & ~1;      // rounded up to pipeline pairs

    // resolved source index for group kk (masked slots -> own node row)
    auto gidx = [&](int kk, int s0_, int M_, int nn) -> int {
        int iv = 4 * kk + g;
        int ld = sorted_src[s0_ + ((iv > 0) ? iv - 1 : 0)];  // padded region
        return (iv == 0 || iv >= M_) ? nn : ld;
    };
    auto grow = [&](int s) -> f16x8 {
        return *(const f16x8*)(xl + (size_t)s * 128 + hl * 8);
    };

    f32x8 acc0 = {0.f, 0.f, 0.f, 0.f, 0.f, 0.f, 0.f, 0.f};
    f32x8 acc1 = {0.f, 0.f, 0.f, 0.f, 0.f, 0.f, 0.f, 0.f};
    float den0 = 0.f, den1 = 0.f;

    auto cone = [&](int kk, f16x8 a, f16x8 b4_, int M_, float& den_, f32x8& acc_) {
        float p = red(score(a, b4_));
        float e = (4 * kk + g < M_) ? exp2f(p) : 0.f;
        den_ += e;
#pragma unroll
        for (int i = 0; i < 8; i++)
            acc_[i] = fmaf((float)a[i], e, acc_[i]);   // v_fma_mix
    };

    // 3-stage pipeline: idx[k+2..k+3] || row[k..k+1 arriving] || compute[k-2..k-1]
    int i00 = gidx(0, s00, M0, n0), i01 = gidx(0, s01, M1, n1);
    int i10 = gidx(1, s00, M0, n0), i11 = gidx(1, s01, M1, n1);
    f16x8 r00 = grow(i00), r01 = grow(i01), r10 = grow(i10), r11 = grow(i11);
    int j00 = gidx(2, s00, M0, n0), j01 = gidx(2, s01, M1, n1);
    int j10 = gidx(3, s00, M0, n0), j11 = gidx(3, s01, M1, n1);

    for (int k = 2; k < KK; k += 2) {
        f16x8 t00 = grow(j00), t01 = grow(j01), t10 = grow(j10), t11 = grow(j11);
        j00 = gidx(k + 2, s00, M0, n0); j01 = gidx(k + 2, s01, M1, n1);
        j10 = gidx(k + 3, s00, M0, n0); j11 = gidx(k + 3, s01, M1, n1);
        cone(k - 2, r00, b40, M0, den0, acc0);
        cone(k - 2, r01, b41, M1, den1, acc1);
        cone(k - 1, r10, b40, M0, den0, acc0);
        cone(k - 1, r11, b41, M1, den1, acc1);
        r00 = t00; r01 = t01; r10 = t10; r11 = t11;
    }
    cone(KK - 2, r00, b40, M0, den0, acc0);
    cone(KK - 2, r01, b41, M1, den1, acc1);
    cone(KK - 1, r10, b40, M0, den0, acc0);
    cone(KK - 1, r11, b41, M1, den1, acc1);

    // combine the 4 edge-groups (feature-aligned): masks 16 and 32 only.
    den0 += __shfl_xor(den0, 16, 64);
    den0 += __shfl_xor(den0, 32, 64);
    den1 += __shfl_xor(den1, 16, 64);
    den1 += __shfl_xor(den1, 32, 64);
#pragma unroll
    for (int i = 0; i < 8; i++) {
        acc0[i] += __shfl_xor(acc0[i], 16, 64);
        acc0[i] += __shfl_xor(acc0[i], 32, 64);
        acc1[i] += __shfl_xor(acc1[i], 16, 64);
        acc1[i] += __shfl_xor(acc1[i], 32, 64);
    }

    // lanes 0-15 store node0, lanes 16-31 store node1 (parallel epilogue)
    const int which = lane >> 4;
    if (which == 0 || (which == 1 && has1)) {
        float inv = 1.0f / (which == 0 ? den0 : den1);
        int nodeo = (which == 0) ? n0 : n1;
        float4 bi0 = *(const float4*)(bias + hl * 8);
        float4 bi1 = *(const float4*)(bias + hl * 8 + 4);
        float o[8];
#pragma unroll
        for (int i = 0; i < 8; i++) {
            float a = (which == 0) ? acc0[i] : acc1[i];
            float b = (i < 4) ? ((i == 0) ? bi0.x : (i == 1) ? bi0.y : (i == 2) ? bi0.z : bi0.w)
                              : ((i == 4) ? bi1.x : (i == 5) ? bi1.y : (i == 6) ? bi1.z : bi1.w);
            o[i] = a * inv + b;
        }
        if (BFOUT) {   // next layer's A: fp16 hi+lo split
            f16x8 hv, lv;
#pragma unroll
            for (int i = 0; i < 8; i++) {
                _Float16 h = (_Float16)o[i];
                hv[i] = h;
                lv[i] = (_Float16)(o[i] - (float)h);
            }
            *(f16x8*)(oh + (size_t)nodeo * 128 + hl * 8) = hv;
            *(f16x8*)(ol + (size_t)nodeo * 128 + hl * 8) = lv;
        } else {
            *(float4*)(outf + (size_t)nodeo * 128 + hl * 8) =
                make_float4(o[0], o[1], o[2], o[3]);
            *(float4*)(outf + (size_t)nodeo * 128 + hl * 8 + 4) =
                make_float4(o[4], o[5], o[6], o[7]);
        }
    }
}

// ---------------------------------------------------------------------------
extern "C" void kernel_launch(void* const* d_in, const int* in_sizes, int n_in,
                              void* d_out, int out_size, void* d_ws, size_t ws_size,
                              hipStream_t stream)
{
    const float* x    = (const float*)d_in[0];
    const int*   ei   = (const int*)d_in[1];
    const float* Wl1  = (const float*)d_in[3];
    const float* Wr1  = (const float*)d_in[4];
    const float* att1 = (const float*)d_in[5];
    const float* b1   = (const float*)d_in[6];
    const float* Wl2  = (const float*)d_in[7];
    const float* Wr2  = (const float*)d_in[8];
    const float* att2 = (const float*)d_in[9];
    const float* b2   = (const float*)d_in[10];
    float* out = (float*)d_out;

    const int N  = in_sizes[0] / 128;
    const int E  = in_sizes[1] / 2;
    const int NB = (N + NPB - 1) / NPB;

    const size_t nf = (size_t)N * 128;
    _Float16* xlf  = (_Float16*)d_ws;                 // nf fp16 (gather array)
    _Float16* xrf  = xlf + nf;                        // nf fp16
    _Float16* ah   = xrf + nf;                        // nf fp16 (A hi: x, then h)
    _Float16* al   = ah + nf;                         // nf fp16 (A lo)
    _Float16* wt   = al + nf;                         // 4*16384 fp16
    int* gcursor   = (int*)(wt + 4 * 16384);          // 256
    int* start     = gcursor + 256;                   // N
    int* deg       = start + N;                       // N
    size_t stgoff  = ((size_t)(deg + N) + 7) & ~(size_t)7;
    int2* staging  = (int2*)stgoff;                   // NB*BCAP int2 (padded)
    int* sorted_src = (int*)(staging + (size_t)NB * BCAP);  // NB*BCAP + 64 ints

    const int grid_chunk = (E + CHUNK - 1) / CHUNK;
    const int node_grid  = (N + 7) / 8;               // 8 nodes per block (2/wave)
    const int gemm_gx    = (N + 127) / 128;
    const int split_grid = (int)((nf / 2 + 255) / 256);

    // ---- zero bucket cursors (captured async op) ----
    hipMemsetAsync(gcursor, 0, 256 * sizeof(int), stream);

    // ---- K1: prep (W fp16-transpose, x hi/lo split) + chunk bucketing ----
    k1_prep_bucket_kernel<<<grid_chunk + 256 + split_grid, 256, 0, stream>>>(
        Wl1, Wr1, Wl2, Wr2, wt, x, ah, al, (int)nf,
        ei, gcursor, staging, E, grid_chunk);

    // ---- K2: per-bucket counting sort + layer-1 GEMM (both halves) ----
    k2_sort_gemm_kernel<<<NB + 2 * gemm_gx, 256, 0, stream>>>(
        staging, gcursor, start, deg, sorted_src, N, NB,
        ah, al, wt + 0 * 16384, wt + 1 * 16384, xlf, xrf, gemm_gx);

    // ---- Layer 1 fused ----
    gat_fused_kernel<2, true><<<node_grid, 256, 0, stream>>>(
        xlf, xrf, att1, b1, start, deg, sorted_src, nullptr, ah, al, N);

    // ---- Layer 2: GEMM + fused ----
    gemm_f16_kernel<<<dim3(gemm_gx, 2), 256, 0, stream>>>(
        ah, al, wt + 2 * 16384, wt + 3 * 16384, xlf, xrf, N);
    gat_fused_kernel<1, false><<<node_grid, 256, 0, stream>>>(
        xlf, xrf, att2, b2, start, deg, sorted_src, out, nullptr, nullptr, N);
}